// Round 8
// baseline (210.430 us; speedup 1.0000x reference)
//
#include <hip/hip_runtime.h>
#include <cstdint>

#define IN_DIM 2048   // 2H
#define H_DIM  1024
#define BROWS  2048   // B*R
#define BATCH  64
#define ROUNDS 32

typedef __bf16 bf16x8 __attribute__((ext_vector_type(8)));
typedef float  f32x4  __attribute__((ext_vector_type(4)));
typedef unsigned short u16;
typedef u16 u16x8 __attribute__((ext_vector_type(8)));

// fp32 -> bf16 (RNE)
__device__ __forceinline__ u16 f2bf(float f) {
    unsigned int u = __float_as_uint(f);
    u += 0x7FFFu + ((u >> 16) & 1u);
    return (u16)(u >> 16);
}

// async global->LDS, 16 bytes/lane. LDS dest is wave-uniform base; HW adds lane*16.
__device__ __forceinline__ void async_ld16(const void* g, void* l) {
    __builtin_amdgcn_global_load_lds(
        (__attribute__((address_space(1))) void*)(uintptr_t)g,
        (__attribute__((address_space(3))) void*)(unsigned int)(uintptr_t)l,
        16, 0, 0);
}

#define BAR()    asm volatile("s_barrier" ::: "memory")
#define LGKM0()  asm volatile("s_waitcnt lgkmcnt(0)" ::: "memory")
#define VMCNT6() asm volatile("s_waitcnt vmcnt(6)" ::: "memory")
#define VMCNT0() asm volatile("s_waitcnt vmcnt(0)" ::: "memory")

// ---------------- 1. prep: input bf16 convert + fused weight transpose (UNCHANGED r3) -------
__global__ __launch_bounds__(256) void prep(
    const float* __restrict__ hist, const float* __restrict__ ques,
    u16* __restrict__ xh, u16* __restrict__ xq,
    const float* __restrict__ why, const float* __restrict__ whg,
    const float* __restrict__ wqy, const float* __restrict__ wqg,
    u16* __restrict__ oh, u16* __restrict__ oq)
{
    int idx = blockIdx.x;
    if (idx < 4096) {
        int i = idx * 256 + threadIdx.x;
        const float4* h4 = (const float4*)hist;
        const float4* q4 = (const float4*)ques;
        float4 a = h4[i], b = q4[i];
        ushort4 oa, ob;
        oa.x = f2bf(a.x); oa.y = f2bf(a.y); oa.z = f2bf(a.z); oa.w = f2bf(a.w);
        ob.x = f2bf(b.x); ob.y = f2bf(b.y); ob.z = f2bf(b.z); ob.w = f2bf(b.w);
        ((ushort4*)xh)[i] = oa;
        ((ushort4*)xq)[i] = ob;
        return;
    }
    int zz = idx - 4096;              // 0..1023
    int z  = zz >> 9;
    int rem = zz & 511;
    int bk = rem >> 5;                // 16 k-tiles of 128
    int bn = rem & 31;                // 32 n-tiles of 64
    const float* Y = z == 0 ? why : wqy;
    const float* G = z == 0 ? whg : wqg;
    u16* O = z == 0 ? oh : oq;
    int k0 = bk << 7, c0 = bn << 5, n0 = bn << 6;

    __shared__ float t[2][128][33];
    int tid = threadIdx.x;
    int row = tid >> 3, cg = (tid & 7) << 2;        // 32 rows x 8 float4-groups
    #pragma unroll
    for (int p = 0; p < 4; p++) {
        int k = row + 32 * p;
        float4 vy = *(const float4*)&Y[(size_t)(k0 + k) * H_DIM + c0 + cg];
        float4 vg = *(const float4*)&G[(size_t)(k0 + k) * H_DIM + c0 + cg];
        t[0][k][cg + 0] = vy.x; t[0][k][cg + 1] = vy.y;
        t[0][k][cg + 2] = vy.z; t[0][k][cg + 3] = vy.w;
        t[1][k][cg + 0] = vg.x; t[1][k][cg + 1] = vg.y;
        t[1][k][cg + 2] = vg.z; t[1][k][cg + 3] = vg.w;
    }
    __syncthreads();
    int j4 = tid >> 4, kg = tid & 15;               // 16 rows x 16 k-groups of 8
    #pragma unroll
    for (int p = 0; p < 4; p++) {
        int j = j4 + 16 * p;                        // 0..63 output row within tile
        int mat = (j >> 4) & 1;                     // 0 = Y (tanh), 1 = G (gate)
        int lc = ((j >> 5) << 4) | (j & 15);        // local source col 0..31
        u16x8 pk;
        #pragma unroll
        for (int e = 0; e < 8; e++)
            pk[e] = f2bf(t[mat][kg * 8 + e][lc]);
        *(u16x8*)&O[(size_t)(n0 + j) * IN_DIM + k0 + kg * 8] = pk;
    }
}

// ---------------- 2. bf16 MFMA GEMM, BM=256 x BN=128, BK=64 dbuf (EXACT r3 revert) ----------
// Best measured config (42.6 us). LDS-pipe-bound at this problem size: all schedule variants
// (2-phase, ping-pong counted-vmcnt, depth-3 quad-buffer) land 43-48 us with MfmaUtil ~30%.
__global__ __launch_bounds__(512, 2) void gemm_act(
    const u16* __restrict__ xh, const u16* __restrict__ xq,
    const u16* __restrict__ wth, const u16* __restrict__ wtq,
    const float* __restrict__ bhy, const float* __restrict__ bhg,
    const float* __restrict__ bqy, const float* __restrict__ bqg,
    u16* __restrict__ eh, u16* __restrict__ eq)
{
    int L = blockIdx.x;
    int cluster = L & 7;          // -> XCD via id%8
    int slot = L >> 3;            // 0..31 within cluster
    int z = cluster >> 2;
    int y = (cluster & 1) * 4 + (slot >> 3);          // 0..7  (M blocks of 256)
    int x = ((cluster >> 1) & 1) * 8 + (slot & 7);    // 0..15 (N blocks of 128)
    int m0 = y * 256, n0 = x * 128;

    const u16* A  = z == 0 ? xh : xq;
    const u16* Bt = z == 0 ? wth : wtq;
    const float* by = z == 0 ? bhy : bqy;
    const float* bg = z == 0 ? bhg : bqg;
    u16* E = z == 0 ? eh : eq;

    __shared__ __align__(16) u16 As[2][256 * 64];
    __shared__ __align__(16) u16 Bs[2][128 * 64];

    int tid = threadIdx.x;
    int wave = tid >> 6, lane = tid & 63;
    int lane15 = lane & 15, quad = lane >> 4;
    int wm = (wave & 3) * 64;     // 4 waves along M
    int wn = (wave >> 2) * 64;    // 2 waves along N

    f32x4 acc[4][4];
    #pragma unroll
    for (int i = 0; i < 4; i++)
        #pragma unroll
        for (int j = 0; j < 4; j++) acc[i][j] = (f32x4){0.f, 0.f, 0.f, 0.f};

    int sArow[4], sAkc[4], sAcb[4];
    #pragma unroll
    for (int r2 = 0; r2 < 4; r2++) {
        int cbase = r2 * 512 + wave * 64;
        int cs = cbase + lane;
        int row = cs >> 3, s = cs & 7;
        sArow[r2] = row; sAkc[r2] = s ^ (row & 7); sAcb[r2] = cbase;
    }
    int sBrow[2], sBkc[2], sBcb[2];
    #pragma unroll
    for (int r2 = 0; r2 < 2; r2++) {
        int cbase = r2 * 512 + wave * 64;
        int cs = cbase + lane;
        int row = cs >> 3, s = cs & 7;
        sBrow[r2] = row; sBkc[r2] = s ^ (row & 7); sBcb[r2] = cbase;
    }

    #define STAGE(buf, kt)                                                                    \
        _Pragma("unroll")                                                                     \
        for (int r2 = 0; r2 < 4; r2++)                                                        \
            async_ld16(A + (size_t)(m0 + sArow[r2]) * IN_DIM + (kt) + sAkc[r2] * 8,           \
                       &As[buf][sAcb[r2] * 8]);                                               \
        _Pragma("unroll")                                                                     \
        for (int r2 = 0; r2 < 2; r2++)                                                        \
            async_ld16(Bt + (size_t)(n0 + sBrow[r2]) * IN_DIM + (kt) + sBkc[r2] * 8,          \
                       &Bs[buf][sBcb[r2] * 8]);

    bf16x8 a0[4], b0[4], a1[4], b1[4];

    #define DSREAD(da, db, buf, ks)                                                           \
        _Pragma("unroll")                                                                     \
        for (int i = 0; i < 4; i++) {                                                         \
            int row = wm + i * 16 + lane15;                                                   \
            int s = ((ks) * 4 + quad) ^ (row & 7);                                            \
            da[i] = *(const bf16x8*)&As[buf][row * 64 + s * 8];                               \
            int rowb = wn + i * 16 + lane15;                                                  \
            int sb = ((ks) * 4 + quad) ^ (rowb & 7);                                          \
            db[i] = *(const bf16x8*)&Bs[buf][rowb * 64 + sb * 8];                             \
        }

    #define MFMA16(fa, fb)                                                                    \
        __builtin_amdgcn_s_setprio(1);                                                        \
        _Pragma("unroll")                                                                     \
        for (int i = 0; i < 4; i++)                                                           \
            _Pragma("unroll")                                                                 \
            for (int j = 0; j < 4; j++)                                                       \
                acc[i][j] = __builtin_amdgcn_mfma_f32_16x16x32_bf16(                          \
                    fa[i], fb[j], acc[i][j], 0, 0, 0);                                        \
        __builtin_amdgcn_s_setprio(0);

    STAGE(0, 0)
    STAGE(1, 64)
    VMCNT6(); BAR();
    DSREAD(a0, b0, 0, 0)

    #pragma unroll 1
    for (int kt = 0; kt < IN_DIM; kt += 128) {
        DSREAD(a1, b1, 0, 1)
        MFMA16(a0, b0)
        LGKM0(); BAR();
        if (kt + 128 < IN_DIM) { STAGE(0, kt + 128) VMCNT6(); }
        else                   { VMCNT0(); }
        BAR();
        DSREAD(a0, b0, 1, 0)
        MFMA16(a1, b1)
        DSREAD(a1, b1, 1, 1)
        MFMA16(a0, b0)
        if (kt + 128 < IN_DIM) {
            LGKM0(); BAR();
            STAGE(1, kt + 192)
            VMCNT6(); BAR();
            DSREAD(a0, b0, 0, 0)
        }
        MFMA16(a1, b1)
    }
    #undef STAGE
    #undef DSREAD
    #undef MFMA16

    int n0w = n0 + wn;
    #pragma unroll
    for (int jp = 0; jp < 2; jp++) {
        int hc = (n0w >> 1) + jp * 16 + lane15;
        float vy = by[hc], vg = bg[hc];
        #pragma unroll
        for (int i = 0; i < 4; i++) {
            #pragma unroll
            for (int r = 0; r < 4; r++) {
                int row = m0 + wm + i * 16 + quad * 4 + r;
                float y2 = tanhf(acc[i][2 * jp][r] + vy);
                float g = acc[i][2 * jp + 1][r] + vg;
                E[(size_t)row * H_DIM + hc] = f2bf(y2 * (g > 0.f ? g : 0.01f * g));
            }
        }
    }
}

// ---------------- 3. score_feat v2: b-blocked for hist/E reuse ------------------------------
// 256 blocks = (q-group qg 0..3) x (batch b 0..63); XCD = b%8 (all blocks of b share L2 slice).
// Each block: 8 q's. Phase A: wave w computes score rows qi=w,w+4 (serial h wave-dots).
// Phase B: masked softmax per qi in-wave. Phase C: ONE pass over hist rows 0..maxq
// accumulating all 8 outputs (weights transposed in LDS, zeros mask h>q).
// Traffic vs v1: hist reads 264->40 MB, Eh reads 71->10 MB.
__global__ __launch_bounds__(256) void score_feat(
    const u16* __restrict__ eh, const u16* __restrict__ eq,
    const float* __restrict__ hist, const float* __restrict__ watt,
    const float* __restrict__ batt, float* __restrict__ out)
{
    int idx = blockIdx.x;
    int b = idx & 63, qg = idx >> 6;       // qg 0..3
    int q0 = qg * 8, maxq = q0 + 7;
    int tid = threadIdx.x, wave = tid >> 6, lane = tid & 63;
    __shared__ float sw[8][32];            // raw scores [qi][h]
    __shared__ float wt[32][8];            // normalized weights, transposed [h][qi]

    ((float*)wt)[tid] = 0.f;               // mask zeros for h > q (256 floats exactly)

    // ---- phase A: scores ----
    for (int qi = wave; qi < 8; qi += 4) {
        int q = q0 + qi;
        const u16* qe = eq + (size_t)(b * ROUNDS + q) * H_DIM;
        float uw[16], u2[16];
        #pragma unroll
        for (int c = 0; c < 2; c++) {
            uint4 pk = ((const uint4*)qe)[lane + 64 * c];     // 8 bf16
            float4 w0 = ((const float4*)watt)[(lane + 64 * c) * 2];
            float4 w1 = ((const float4*)watt)[(lane + 64 * c) * 2 + 1];
            unsigned int ws[4] = {pk.x, pk.y, pk.z, pk.w};
            float wf[8] = {w0.x, w0.y, w0.z, w0.w, w1.x, w1.y, w1.z, w1.w};
            #pragma unroll
            for (int e = 0; e < 4; e++) {
                float lo = __uint_as_float(ws[e] << 16);
                float hi = __uint_as_float(ws[e] & 0xFFFF0000u);
                uw[c * 8 + 2 * e]     = lo * wf[2 * e];
                u2[c * 8 + 2 * e]     = lo * lo;
                uw[c * 8 + 2 * e + 1] = hi * wf[2 * e + 1];
                u2[c * 8 + 2 * e + 1] = hi * hi;
            }
        }
        for (int h = 0; h <= q; h++) {
            const u16* he = eh + (size_t)(b * ROUNDS + h) * H_DIM;
            float num = 0.f, nrm = 0.f;
            #pragma unroll
            for (int c = 0; c < 2; c++) {
                uint4 pk = ((const uint4*)he)[lane + 64 * c];
                unsigned int vs[4] = {pk.x, pk.y, pk.z, pk.w};
                #pragma unroll
                for (int e = 0; e < 4; e++) {
                    float lo = __uint_as_float(vs[e] << 16);
                    float hi = __uint_as_float(vs[e] & 0xFFFF0000u);
                    num += uw[c * 8 + 2 * e] * lo + uw[c * 8 + 2 * e + 1] * hi;
                    nrm += u2[c * 8 + 2 * e] * lo * lo + u2[c * 8 + 2 * e + 1] * hi * hi;
                }
            }
            #pragma unroll
            for (int off = 32; off > 0; off >>= 1) {
                num += __shfl_down(num, off);
                nrm += __shfl_down(nrm, off);
            }
            if (lane == 0)
                sw[qi][h] = num / fmaxf(sqrtf(nrm), 1e-12f) + batt[0];
        }
    }
    __syncthreads();

    // ---- phase B: masked softmax per qi (both 32-lane halves compute; lane<32 writes) ----
    for (int qi = wave; qi < 8; qi += 4) {
        int q = q0 + qi;
        int h = lane & 31;
        bool v = (h <= q);
        float s = v ? sw[qi][h] : -1e30f;
        float mx = s;
        #pragma unroll
        for (int off = 16; off > 0; off >>= 1)
            mx = fmaxf(mx, __shfl_xor(mx, off));
        float e = v ? expf(s - mx) : 0.f;
        float zs = e;
        #pragma unroll
        for (int off = 16; off > 0; off >>= 1)
            zs += __shfl_xor(zs, off);
        if (v && lane < 32) wt[h][qi] = e / zs;
    }
    __syncthreads();

    // ---- phase C: shared hist pass, 8 outputs at once ----
    const float4* hb = (const float4*)(hist + (size_t)b * ROUNDS * IN_DIM);
    float4* ob = (float4*)(out + (size_t)(b * ROUNDS + q0) * IN_DIM);
    #pragma unroll
    for (int cc = 0; cc < 2; cc++) {
        int c = tid + cc * 256;            // 0..511 float4 column
        float4 a[8];
        #pragma unroll
        for (int qi = 0; qi < 8; qi++) a[qi] = (float4){0.f, 0.f, 0.f, 0.f};
        for (int h = 0; h <= maxq; h++) {
            float4 x = hb[h * 512 + c];
            float4 wa = *(const float4*)&wt[h][0];   // uniform LDS broadcast
            float4 wb = *(const float4*)&wt[h][4];
            float w8[8] = {wa.x, wa.y, wa.z, wa.w, wb.x, wb.y, wb.z, wb.w};
            #pragma unroll
            for (int qi = 0; qi < 8; qi++) {
                a[qi].x += w8[qi] * x.x; a[qi].y += w8[qi] * x.y;
                a[qi].z += w8[qi] * x.z; a[qi].w += w8[qi] * x.w;
            }
        }
        #pragma unroll
        for (int qi = 0; qi < 8; qi++)
            ob[qi * 512 + c] = a[qi];
    }
}

extern "C" void kernel_launch(void* const* d_in, const int* in_sizes, int n_in,
                              void* d_out, int out_size, void* d_ws, size_t ws_size,
                              hipStream_t stream) {
    const float* hist = (const float*)d_in[0];
    const float* ques = (const float*)d_in[1];
    const float* Why  = (const float*)d_in[2];
    const float* bhy  = (const float*)d_in[3];
    const float* Whg  = (const float*)d_in[4];
    const float* bhg  = (const float*)d_in[5];
    const float* Wqy  = (const float*)d_in[6];
    const float* bqy  = (const float*)d_in[7];
    const float* Wqg  = (const float*)d_in[8];
    const float* bqg  = (const float*)d_in[9];
    const float* watt = (const float*)d_in[10];
    const float* batt = (const float*)d_in[11];
    float* out = (float*)d_out;

    // workspace (~42 MB)
    char* w = (char*)d_ws;
    u16* Xh  = (u16*)w;                               // [2048,2048] bf16
    u16* Xq  = Xh  + (size_t)BROWS * IN_DIM;
    u16* WtH = Xq  + (size_t)BROWS * IN_DIM;          // [2048,2048] bf16 fused-interleaved
    u16* WtQ = WtH + (size_t)IN_DIM * IN_DIM;
    u16* Eh  = WtQ + (size_t)IN_DIM * IN_DIM;         // [2048,1024] bf16
    u16* Eq  = Eh  + (size_t)BROWS * H_DIM;

    prep<<<5120, 256, 0, stream>>>(hist, ques, Xh, Xq, Why, Whg, Wqy, Wqg, WtH, WtQ);
    gemm_act<<<256, 512, 0, stream>>>(Xh, Xq, WtH, WtQ, bhy, bhg, bqy, bqg, Eh, Eq);
    score_feat<<<256, 256, 0, stream>>>(Eh, Eq, hist, watt, batt, out);
}

// Round 9
// 179.468 us; speedup vs baseline: 1.1725x; 1.1725x over previous
//
#include <hip/hip_runtime.h>
#include <cstdint>

#define IN_DIM 2048   // 2H
#define H_DIM  1024
#define BROWS  2048   // B*R
#define BATCH  64
#define ROUNDS 32

typedef __bf16 bf16x8 __attribute__((ext_vector_type(8)));
typedef float  f32x4  __attribute__((ext_vector_type(4)));
typedef unsigned short u16;
typedef u16 u16x8 __attribute__((ext_vector_type(8)));

// fp32 -> bf16 (RNE)
__device__ __forceinline__ u16 f2bf(float f) {
    unsigned int u = __float_as_uint(f);
    u += 0x7FFFu + ((u >> 16) & 1u);
    return (u16)(u >> 16);
}

// async global->LDS, 16 bytes/lane. LDS dest is wave-uniform base; HW adds lane*16.
__device__ __forceinline__ void async_ld16(const void* g, void* l) {
    __builtin_amdgcn_global_load_lds(
        (__attribute__((address_space(1))) void*)(uintptr_t)g,
        (__attribute__((address_space(3))) void*)(unsigned int)(uintptr_t)l,
        16, 0, 0);
}

#define BAR()    asm volatile("s_barrier" ::: "memory")
#define LGKM0()  asm volatile("s_waitcnt lgkmcnt(0)" ::: "memory")
#define VMCNT6() asm volatile("s_waitcnt vmcnt(6)" ::: "memory")
#define VMCNT0() asm volatile("s_waitcnt vmcnt(0)" ::: "memory")

// ---------------- 1. prep: input bf16 convert + fused weight transpose ----------------------
__global__ __launch_bounds__(256) void prep(
    const float* __restrict__ hist, const float* __restrict__ ques,
    u16* __restrict__ xh, u16* __restrict__ xq,
    const float* __restrict__ why, const float* __restrict__ whg,
    const float* __restrict__ wqy, const float* __restrict__ wqg,
    u16* __restrict__ oh, u16* __restrict__ oq)
{
    int idx = blockIdx.x;
    if (idx < 4096) {
        int i = idx * 256 + threadIdx.x;
        const float4* h4 = (const float4*)hist;
        const float4* q4 = (const float4*)ques;
        float4 a = h4[i], b = q4[i];
        ushort4 oa, ob;
        oa.x = f2bf(a.x); oa.y = f2bf(a.y); oa.z = f2bf(a.z); oa.w = f2bf(a.w);
        ob.x = f2bf(b.x); ob.y = f2bf(b.y); ob.z = f2bf(b.z); ob.w = f2bf(b.w);
        ((ushort4*)xh)[i] = oa;
        ((ushort4*)xq)[i] = ob;
        return;
    }
    int zz = idx - 4096;              // 0..1023
    int z  = zz >> 9;
    int rem = zz & 511;
    int bk = rem >> 5;                // 16 k-tiles of 128
    int bn = rem & 31;                // 32 n-tiles of 64
    const float* Y = z == 0 ? why : wqy;
    const float* G = z == 0 ? whg : wqg;
    u16* O = z == 0 ? oh : oq;
    int k0 = bk << 7, c0 = bn << 5, n0 = bn << 6;

    __shared__ float t[2][128][33];
    int tid = threadIdx.x;
    int row = tid >> 3, cg = (tid & 7) << 2;        // 32 rows x 8 float4-groups
    #pragma unroll
    for (int p = 0; p < 4; p++) {
        int k = row + 32 * p;
        float4 vy = *(const float4*)&Y[(size_t)(k0 + k) * H_DIM + c0 + cg];
        float4 vg = *(const float4*)&G[(size_t)(k0 + k) * H_DIM + c0 + cg];
        t[0][k][cg + 0] = vy.x; t[0][k][cg + 1] = vy.y;
        t[0][k][cg + 2] = vy.z; t[0][k][cg + 3] = vy.w;
        t[1][k][cg + 0] = vg.x; t[1][k][cg + 1] = vg.y;
        t[1][k][cg + 2] = vg.z; t[1][k][cg + 3] = vg.w;
    }
    __syncthreads();
    int j4 = tid >> 4, kg = tid & 15;               // 16 rows x 16 k-groups of 8
    #pragma unroll
    for (int p = 0; p < 4; p++) {
        int j = j4 + 16 * p;                        // 0..63 output row within tile
        int mat = (j >> 4) & 1;                     // 0 = Y (tanh), 1 = G (gate)
        int lc = ((j >> 5) << 4) | (j & 15);        // local source col 0..31
        u16x8 pk;
        #pragma unroll
        for (int e = 0; e < 8; e++)
            pk[e] = f2bf(t[mat][kg * 8 + e][lc]);
        *(u16x8*)&O[(size_t)(n0 + j) * IN_DIM + k0 + kg * 8] = pk;
    }
}

// ---------------- 2. bf16 MFMA GEMM, BM=256 x BN=128, BK=64 dbuf (r3-best, 42.6 us) ---------
// LDS-latency/structure-bound at this shape: schedule variants (2-phase, ping-pong counted
// vmcnt, depth-3 quad-buffer) and occupancy variants (2-4 waves/SIMD) all land 43-48 us,
// MfmaUtil ~30%, consistent with the m102 shape-curve ceiling at N=2048.
__global__ __launch_bounds__(512, 2) void gemm_act(
    const u16* __restrict__ xh, const u16* __restrict__ xq,
    const u16* __restrict__ wth, const u16* __restrict__ wtq,
    const float* __restrict__ bhy, const float* __restrict__ bhg,
    const float* __restrict__ bqy, const float* __restrict__ bqg,
    u16* __restrict__ eh, u16* __restrict__ eq)
{
    int L = blockIdx.x;
    int cluster = L & 7;          // -> XCD via id%8
    int slot = L >> 3;            // 0..31 within cluster
    int z = cluster >> 2;
    int y = (cluster & 1) * 4 + (slot >> 3);          // 0..7  (M blocks of 256)
    int x = ((cluster >> 1) & 1) * 8 + (slot & 7);    // 0..15 (N blocks of 128)
    int m0 = y * 256, n0 = x * 128;

    const u16* A  = z == 0 ? xh : xq;
    const u16* Bt = z == 0 ? wth : wtq;
    const float* by = z == 0 ? bhy : bqy;
    const float* bg = z == 0 ? bhg : bqg;
    u16* E = z == 0 ? eh : eq;

    __shared__ __align__(16) u16 As[2][256 * 64];
    __shared__ __align__(16) u16 Bs[2][128 * 64];

    int tid = threadIdx.x;
    int wave = tid >> 6, lane = tid & 63;
    int lane15 = lane & 15, quad = lane >> 4;
    int wm = (wave & 3) * 64;     // 4 waves along M
    int wn = (wave >> 2) * 64;    // 2 waves along N

    f32x4 acc[4][4];
    #pragma unroll
    for (int i = 0; i < 4; i++)
        #pragma unroll
        for (int j = 0; j < 4; j++) acc[i][j] = (f32x4){0.f, 0.f, 0.f, 0.f};

    int sArow[4], sAkc[4], sAcb[4];
    #pragma unroll
    for (int r2 = 0; r2 < 4; r2++) {
        int cbase = r2 * 512 + wave * 64;
        int cs = cbase + lane;
        int row = cs >> 3, s = cs & 7;
        sArow[r2] = row; sAkc[r2] = s ^ (row & 7); sAcb[r2] = cbase;
    }
    int sBrow[2], sBkc[2], sBcb[2];
    #pragma unroll
    for (int r2 = 0; r2 < 2; r2++) {
        int cbase = r2 * 512 + wave * 64;
        int cs = cbase + lane;
        int row = cs >> 3, s = cs & 7;
        sBrow[r2] = row; sBkc[r2] = s ^ (row & 7); sBcb[r2] = cbase;
    }

    #define STAGE(buf, kt)                                                                    \
        _Pragma("unroll")                                                                     \
        for (int r2 = 0; r2 < 4; r2++)                                                        \
            async_ld16(A + (size_t)(m0 + sArow[r2]) * IN_DIM + (kt) + sAkc[r2] * 8,           \
                       &As[buf][sAcb[r2] * 8]);                                               \
        _Pragma("unroll")                                                                     \
        for (int r2 = 0; r2 < 2; r2++)                                                        \
            async_ld16(Bt + (size_t)(n0 + sBrow[r2]) * IN_DIM + (kt) + sBkc[r2] * 8,          \
                       &Bs[buf][sBcb[r2] * 8]);

    bf16x8 a0[4], b0[4], a1[4], b1[4];

    #define DSREAD(da, db, buf, ks)                                                           \
        _Pragma("unroll")                                                                     \
        for (int i = 0; i < 4; i++) {                                                         \
            int row = wm + i * 16 + lane15;                                                   \
            int s = ((ks) * 4 + quad) ^ (row & 7);                                            \
            da[i] = *(const bf16x8*)&As[buf][row * 64 + s * 8];                               \
            int rowb = wn + i * 16 + lane15;                                                  \
            int sb = ((ks) * 4 + quad) ^ (rowb & 7);                                          \
            db[i] = *(const bf16x8*)&Bs[buf][rowb * 64 + sb * 8];                             \
        }

    #define MFMA16(fa, fb)                                                                    \
        __builtin_amdgcn_s_setprio(1);                                                        \
        _Pragma("unroll")                                                                     \
        for (int i = 0; i < 4; i++)                                                           \
            _Pragma("unroll")                                                                 \
            for (int j = 0; j < 4; j++)                                                       \
                acc[i][j] = __builtin_amdgcn_mfma_f32_16x16x32_bf16(                          \
                    fa[i], fb[j], acc[i][j], 0, 0, 0);                                        \
        __builtin_amdgcn_s_setprio(0);

    STAGE(0, 0)
    STAGE(1, 64)
    VMCNT6(); BAR();
    DSREAD(a0, b0, 0, 0)

    #pragma unroll 1
    for (int kt = 0; kt < IN_DIM; kt += 128) {
        DSREAD(a1, b1, 0, 1)
        MFMA16(a0, b0)
        LGKM0(); BAR();
        if (kt + 128 < IN_DIM) { STAGE(0, kt + 128) VMCNT6(); }
        else                   { VMCNT0(); }
        BAR();
        DSREAD(a0, b0, 1, 0)
        MFMA16(a1, b1)
        DSREAD(a1, b1, 1, 1)
        MFMA16(a0, b0)
        if (kt + 128 < IN_DIM) {
            LGKM0(); BAR();
            STAGE(1, kt + 192)
            VMCNT6(); BAR();
            DSREAD(a0, b0, 0, 0)
        }
        MFMA16(a1, b1)
    }
    #undef STAGE
    #undef DSREAD
    #undef MFMA16

    int n0w = n0 + wn;
    #pragma unroll
    for (int jp = 0; jp < 2; jp++) {
        int hc = (n0w >> 1) + jp * 16 + lane15;
        float vy = by[hc], vg = bg[hc];
        #pragma unroll
        for (int i = 0; i < 4; i++) {
            #pragma unroll
            for (int r = 0; r < 4; r++) {
                int row = m0 + wm + i * 16 + quad * 4 + r;
                float y2 = tanhf(acc[i][2 * jp][r] + vy);
                float g = acc[i][2 * jp + 1][r] + vg;
                E[(size_t)row * H_DIM + hc] = f2bf(y2 * (g > 0.f ? g : 0.01f * g));
            }
        }
    }
}

// ---------------- 3. scores + causal softmax + weighted hist sum (r3-best v1) ---------------
// Linear grid idx = q*64 + b => XCD = b%8: all 32 q-blocks of a batch share one XCD L2, so
// the per-batch hist (256 KB) and E rows are L2-resident across q-blocks (measured <25 us;
// the r8 b-blocked variant that "saved" this traffic collapsed occupancy to 6% and cost 51 us).
__global__ __launch_bounds__(256) void score_feat(
    const u16* __restrict__ eh, const u16* __restrict__ eq,
    const float* __restrict__ hist, const float* __restrict__ watt,
    const float* __restrict__ batt, float* __restrict__ out)
{
    int idx = blockIdx.x;
    int b = idx & 63, q = idx >> 6;
    int tid = threadIdx.x, wave = tid >> 6, lane = tid & 63;
    __shared__ float sw[32], swn[32];

    const u16* qe = eq + (size_t)(b * ROUNDS + q) * H_DIM;
    float uw[16], u2[16];
    #pragma unroll
    for (int c = 0; c < 2; c++) {
        uint4 pk = ((const uint4*)qe)[lane + 64 * c];     // 8 bf16
        float4 w0 = ((const float4*)watt)[(lane + 64 * c) * 2];
        float4 w1 = ((const float4*)watt)[(lane + 64 * c) * 2 + 1];
        unsigned int ws[4] = {pk.x, pk.y, pk.z, pk.w};
        float wf[8] = {w0.x, w0.y, w0.z, w0.w, w1.x, w1.y, w1.z, w1.w};
        #pragma unroll
        for (int e = 0; e < 4; e++) {
            float lo = __uint_as_float(ws[e] << 16);
            float hi = __uint_as_float(ws[e] & 0xFFFF0000u);
            uw[c * 8 + 2 * e]     = lo * wf[2 * e];
            u2[c * 8 + 2 * e]     = lo * lo;
            uw[c * 8 + 2 * e + 1] = hi * wf[2 * e + 1];
            u2[c * 8 + 2 * e + 1] = hi * hi;
        }
    }
    for (int h = wave; h <= q; h += 4) {
        const u16* he = eh + (size_t)(b * ROUNDS + h) * H_DIM;
        float num = 0.f, nrm = 0.f;
        #pragma unroll
        for (int c = 0; c < 2; c++) {
            uint4 pk = ((const uint4*)he)[lane + 64 * c];
            unsigned int vs[4] = {pk.x, pk.y, pk.z, pk.w};
            #pragma unroll
            for (int e = 0; e < 4; e++) {
                float lo = __uint_as_float(vs[e] << 16);
                float hi = __uint_as_float(vs[e] & 0xFFFF0000u);
                num += uw[c * 8 + 2 * e] * lo + uw[c * 8 + 2 * e + 1] * hi;
                nrm += u2[c * 8 + 2 * e] * lo * lo + u2[c * 8 + 2 * e + 1] * hi * hi;
            }
        }
        #pragma unroll
        for (int off = 32; off > 0; off >>= 1) {
            num += __shfl_down(num, off);
            nrm += __shfl_down(nrm, off);
        }
        if (lane == 0)
            sw[h] = num / fmaxf(sqrtf(nrm), 1e-12f) + batt[0];
    }
    __syncthreads();
    if (tid < 64) {
        int h = lane & 31;
        bool v = (h <= q);
        float s = v ? sw[h] : -1e30f;
        float mx = s;
        #pragma unroll
        for (int off = 16; off > 0; off >>= 1)
            mx = fmaxf(mx, __shfl_xor(mx, off));
        float e = v ? expf(s - mx) : 0.f;
        float zs = e;
        #pragma unroll
        for (int off = 16; off > 0; off >>= 1)
            zs += __shfl_xor(zs, off);
        if (v && lane < 32) swn[h] = e / zs;
    }
    __syncthreads();
    const float4* hb = (const float4*)(hist + (size_t)b * ROUNDS * IN_DIM);
    float4* ob = (float4*)(out + (size_t)(b * ROUNDS + q) * IN_DIM);
    #pragma unroll
    for (int d0 = 0; d0 < 2; d0++) {
        int d = tid + d0 * 256;          // < 512 float4s
        float4 a = {0.f, 0.f, 0.f, 0.f};
        for (int h = 0; h <= q; h++) {
            float w = swn[h];
            float4 x = hb[h * 512 + d];
            a.x += w * x.x; a.y += w * x.y; a.z += w * x.z; a.w += w * x.w;
        }
        ob[d] = a;
    }
}

extern "C" void kernel_launch(void* const* d_in, const int* in_sizes, int n_in,
                              void* d_out, int out_size, void* d_ws, size_t ws_size,
                              hipStream_t stream) {
    const float* hist = (const float*)d_in[0];
    const float* ques = (const float*)d_in[1];
    const float* Why  = (const float*)d_in[2];
    const float* bhy  = (const float*)d_in[3];
    const float* Whg  = (const float*)d_in[4];
    const float* bhg  = (const float*)d_in[5];
    const float* Wqy  = (const float*)d_in[6];
    const float* bqy  = (const float*)d_in[7];
    const float* Wqg  = (const float*)d_in[8];
    const float* bqg  = (const float*)d_in[9];
    const float* watt = (const float*)d_in[10];
    const float* batt = (const float*)d_in[11];
    float* out = (float*)d_out;

    // workspace (~42 MB)
    char* w = (char*)d_ws;
    u16* Xh  = (u16*)w;                               // [2048,2048] bf16
    u16* Xq  = Xh  + (size_t)BROWS * IN_DIM;
    u16* WtH = Xq  + (size_t)BROWS * IN_DIM;          // [2048,2048] bf16 fused-interleaved
    u16* WtQ = WtH + (size_t)IN_DIM * IN_DIM;
    u16* Eh  = WtQ + (size_t)IN_DIM * IN_DIM;         // [2048,1024] bf16
    u16* Eq  = Eh  + (size_t)BROWS * H_DIM;

    prep<<<5120, 256, 0, stream>>>(hist, ques, Xh, Xq, Why, Whg, Wqy, Wqg, WtH, WtQ);
    gemm_act<<<256, 512, 0, stream>>>(Xh, Xq, WtH, WtQ, bhy, bhg, bqy, bqg, Eh, Eq);
    score_feat<<<2048, 256, 0, stream>>>(Eh, Eq, hist, watt, batt, out);
}